// Round 2
// baseline (299.578 us; speedup 1.0000x reference)
//
#include <hip/hip_runtime.h>
#include <math.h>

// Gaussian NLL + analytic grad + Hessian wrt (mu, pre-softplus-std).
// Pure streaming kernel: 12 B/elem in, 28 B/elem out -> 335.5 MB @ N=2^23.
// Roofline ~53 us @ 6.3 TB/s.
//
// vs the 294.8 us baseline:
//  - nontemporal loads/stores (outputs write-once, inputs read-once; total
//    369 MB > 256 MB L3 so cache allocation only causes mutual eviction).
//    NOTE: builtins need clang ext_vector types, not HIP float2/float4.
//  - grid-stride loop, 2048 blocks x 256 thr (16 elem/thread): independent
//    iterations per thread for ILP / software pipelining.
//  - sigmoid reuses exp(-|s|) from softplus: one fewer v_exp_f32/elem.

typedef float v2f __attribute__((ext_vector_type(2)));
typedef float v4f __attribute__((ext_vector_type(4)));

__global__ __launch_bounds__(256) void unll_kernel(
    const v2f* __restrict__ yp,    // [N] of (mu, s)
    const float* __restrict__ yt,  // [N]
    float* __restrict__ out_loss,  // [N]
    v2f* __restrict__ out_g,       // [N] of (g_mu, g_s)
    v4f* __restrict__ out_h,       // [N] of (h00, h01, h10, h11)
    int n)
{
    const int stride = gridDim.x * blockDim.x;
    for (int i = blockIdx.x * blockDim.x + threadIdx.x; i < n; i += stride) {
        v2f   p = __builtin_nontemporal_load(&yp[i]);
        float y = __builtin_nontemporal_load(&yt[i]);

        float mu = p.x;
        float s  = p.y;

        // stable softplus: max(s,0) + log1p(exp(-|s|))
        float e    = __expf(-fabsf(s));
        float rec  = 1.0f / (1.0f + e);           // = sigmoid(|s|)
        float sig  = (s >= 0.0f) ? rec : e * rec; // sigmoid(s), reuses e
        float stdv = fmaxf(s, 0.0f) + __logf(1.0f + e);
        float inv  = 1.0f / stdv;
        float z    = (y - mu) * inv;
        float z2   = z * z;

        float L  = 0.5f * z2 + __logf(stdv) + 0.91893853320467274178f; // +0.5*log(2*pi)
        float g0 = -z * inv;
        float g1 = sig * (1.0f - z2) * inv;

        float inv2 = inv * inv;
        float h00 = inv2;
        float h01 = 2.0f * z * sig * inv2;
        float h11 = sig * (1.0f - sig) * (1.0f - z2) * inv
                  + sig * sig * (3.0f * z2 - 1.0f) * inv2;

        v2f g; g.x = g0; g.y = g1;
        v4f h; h.x = h00; h.y = h01; h.z = h01; h.w = h11;

        __builtin_nontemporal_store(L, &out_loss[i]);
        __builtin_nontemporal_store(g, &out_g[i]);
        __builtin_nontemporal_store(h, &out_h[i]);
    }
}

extern "C" void kernel_launch(void* const* d_in, const int* in_sizes, int n_in,
                              void* d_out, int out_size, void* d_ws, size_t ws_size,
                              hipStream_t stream) {
    const float* y_pred = (const float*)d_in[0];  // [N,2]
    const float* y_true = (const float*)d_in[1];  // [N]
    float* out = (float*)d_out;                   // loss[N] | d[2N] | dd[4N]

    const int N = in_sizes[1];

    float* out_loss = out;
    v2f*   out_g    = (v2f*)(out + (size_t)N);
    v4f*   out_h    = (v4f*)(out + (size_t)3 * N);

    const int block = 256;
    int grid = (N + block - 1) / block;
    if (grid > 2048) grid = 2048;   // grid-stride: 256 CUs x 8 blocks
    unll_kernel<<<grid, block, 0, stream>>>(
        (const v2f*)y_pred, y_true, out_loss, out_g, out_h, N);
}